// Round 7
// baseline (274.216 us; speedup 1.0000x reference)
//
#include <hip/hip_runtime.h>
#include <stdint.h>

// ---------------------------------------------------------------------------
// Speaker pairwise loss. sim = F·F^T symmetric, 128x128 tiles J>=I (2080).
// R7: amortize per-block fixed costs (measured 9.06 vs 5.4 us*CU/tile for
// 1-tile vs 8-tile blocks): each block = one I-strip x up to 4 J-tiles
// (544 blocks, all resident at once). Row stats live in registers across the
// J-group (one shuffle-reduce + store per block). NO epilogue barriers / LDS
// scratch: partials stored per wave-half (rp[grp][2][128], cp[tile][2][128]);
// reduce kernels fold both halves. Col labels/thresholds: direct global loads.
// Single-buffered BK=64 staging (dbuf measured neutral in R6), XOR swizzle
// (0 conflicts, measured). LDS ~35KB -> 4 blocks/CU by LDS.
// NO atomics. NO forced min-waves bound (R5: spill disaster).
// ws: fb bf16[B*D] | rp0/rp1[544*256] | cp0/cp1[2080*256] | tmn tmx psum nsum
// ---------------------------------------------------------------------------

typedef __attribute__((ext_vector_type(8))) short short8;   // 8 bf16
typedef __attribute__((ext_vector_type(4))) float floatx4;  // MFMA C/D

constexpr int D = 256;
constexpr int BM = 128;
constexpr int NT = 64;                    // 8192/128
constexpr int GJT = 4;                    // J-tiles per block
constexpr int NGRP = 544;                 // sum_I ceil((64-I)/4)
constexpr int NTILE = NT * (NT + 1) / 2;  // 2080

__device__ __forceinline__ int triBase(int I) { return I * (129 - I) / 2; }

__device__ __forceinline__ unsigned f2bf(float f) {  // fp32 -> bf16, RNE
  unsigned u = __float_as_uint(f);
  return (u + 0x7FFFu + ((u >> 16) & 1u)) >> 16;
}

__device__ __forceinline__ void gl_lds16(const void* g, void* l) {
  __builtin_amdgcn_global_load_lds(
      (const __attribute__((address_space(1))) unsigned int*)g,
      (__attribute__((address_space(3))) unsigned int*)l, 16, 0, 0);
}

__global__ void convert_kernel(const float* __restrict__ feats,
                               unsigned short* __restrict__ fb, int n4) {
  int i = blockIdx.x * blockDim.x + threadIdx.x;
  if (i < n4) {
    float4 v = ((const float4*)feats)[i];
    unsigned lo = f2bf(v.x) | (f2bf(v.y) << 16);
    unsigned hi = f2bf(v.z) | (f2bf(v.w) << 16);
    ((uint2*)fb)[i] = make_uint2(lo, hi);
  }
}

template <int PASS>
__global__ __launch_bounds__(256)
void pair_kernel(const unsigned short* __restrict__ fb, const int* __restrict__ labels,
                 const float* __restrict__ tmn, const float* __restrict__ tmx,
                 float* __restrict__ rp0, float* __restrict__ rp1,
                 float* __restrict__ cp0, float* __restrict__ cp1) {
  __shared__ __align__(16) short As[BM * 64];   // 16KB
  __shared__ __align__(16) short Bs[BM * 64];   // 16KB
  __shared__ int   labA[BM];
  __shared__ float tA0[BM], tA1[BM];

  // ---- decode group -> (I, J0, nJ) ----
  int g = blockIdx.x, I = 0;
  for (;;) { int ng = (NT - I + GJT - 1) / GJT; if (g < ng) break; g -= ng; ++I; }
  const int J0 = I + g * GJT;
  const int nJ = min(GJT, NT - J0);
  const int row0 = I * BM;

  const int tid  = threadIdx.x;
  const int lane = tid & 63;
  const int wave = tid >> 6;
  const int l15  = lane & 15;
  const int quad = lane >> 4;
  const int wr   = (wave >> 1) * 64;
  const int wc   = (wave & 1) * 64;

  const float ONE_EPS = 1.0f - 1e-5f;
  const float INF = __builtin_inff();

  // staging geometry (BK=64): wave covers 32 rows, 8 lanes/row, 16B/lane
  const int srow = (wave << 5) + (lane >> 3);
  const int slot = lane & 7;

  auto stage = [&](int kc, int col0) {
#pragma unroll
    for (int j = 0; j < 4; ++j) {
      int r = srow + 8 * j;
      int sw = (slot ^ (r & 7)) << 4;     // XOR swizzle (0 conflicts, measured)
      const char* ga = (const char*)fb + (((size_t)(row0 + r)) << 9) + (kc << 7) + sw;
      const char* gb = (const char*)fb + (((size_t)(col0 + r)) << 9) + (kc << 7) + sw;
      gl_lds16(ga, (char*)As + (r << 7) + (slot << 4));
      gl_lds16(gb, (char*)Bs + (r << 7) + (slot << 4));
    }
  };

  if (tid < BM) {                         // once per block; covered by first barrier
    labA[tid] = labels[row0 + tid];
    if (PASS == 2) {
      tA0[tid] = tmn[row0 + tid];
      tA1[tid] = tmx[row0 + tid];
    }
  }

  int arow[4], brow[4];
#pragma unroll
  for (int i = 0; i < 4; ++i) {
    arow[i] = wr + i * 16 + l15;
    brow[i] = wc + i * 16 + l15;
  }

  // row stats: accumulate across the whole J-group in registers
  float s0[16], s1[16];
#pragma unroll
  for (int i = 0; i < 16; ++i) {
    s0[i] = (PASS == 1) ? INF : 0.f;
    s1[i] = (PASS == 1) ? -INF : 0.f;
  }

  for (int jt = 0; jt < nJ; ++jt) {
    const int J = J0 + jt;
    const int col0 = J * BM;
    const bool diag = (J == I);
    const int t = triBase(I) + (J - I);   // tile id for cp store

    // per-tile col labels/thresholds: direct global (L1-hot)
    int labc[4];
    float tBn[4], tBx[4];
#pragma unroll
    for (int cf = 0; cf < 4; ++cf) {
      int ci = col0 + wc + cf * 16 + l15;
      labc[cf] = labels[ci];
      if (PASS == 2) { tBn[cf] = tmn[ci]; tBx[cf] = tmx[ci]; }
    }

    floatx4 acc[4][4];
#pragma unroll
    for (int rf = 0; rf < 4; ++rf)
#pragma unroll
      for (int cf = 0; cf < 4; ++cf)
        acc[rf][cf] = (floatx4)(0.f);

    for (int kc = 0; kc < 4; ++kc) {
      stage(kc, col0);
      __syncthreads();                    // staging landed
#pragma unroll
      for (int ks = 0; ks < 2; ++ks) {
        const int gg = ks * 4 + quad;
        short8 a[4], b[4];
#pragma unroll
        for (int rf = 0; rf < 4; ++rf)
          a[rf] = *(const short8*)(As + arow[rf] * 64 + ((gg ^ (arow[rf] & 7)) << 3));
#pragma unroll
        for (int cf = 0; cf < 4; ++cf)
          b[cf] = *(const short8*)(Bs + brow[cf] * 64 + ((gg ^ (brow[cf] & 7)) << 3));
#pragma unroll
        for (int rf = 0; rf < 4; ++rf)
#pragma unroll
          for (int cf = 0; cf < 4; ++cf)
            acc[rf][cf] = __builtin_amdgcn_mfma_f32_16x16x32_bf16(a[rf], b[cf], acc[rf][cf], 0, 0, 0);
      }
      __syncthreads();                    // all ds_reads done before next stage
    }

    // ---- epilogue (no barriers, no LDS scratch) ----
    float c0[4], c1[4];
#pragma unroll
    for (int i = 0; i < 4; ++i) {
      c0[i] = (PASS == 1) ? INF : 0.f;
      c1[i] = (PASS == 1) ? -INF : 0.f;
    }

#pragma unroll
    for (int rf = 0; rf < 4; ++rf) {
#pragma unroll
      for (int r = 0; r < 4; ++r) {
        const int ri = wr + rf * 16 + quad * 4 + r;
        const int lr = labA[ri];
        float tRn = 0.f, tRx = 0.f;
        if (PASS == 2) { tRn = tA0[ri]; tRx = tA1[ri]; }
#pragma unroll
        for (int cf = 0; cf < 4; ++cf) {
          float sim = acc[rf][cf][r];
          bool same = (lr == labc[cf]);
          bool posok = same && (sim < ONE_EPS);
          if (PASS == 1) {
            float pc = posok ? sim : INF;
            float nc = same ? -INF : sim;
            s0[rf * 4 + r] = fminf(s0[rf * 4 + r], pc);
            s1[rf * 4 + r] = fmaxf(s1[rf * 4 + r], nc);
            c0[cf] = fminf(c0[cf], pc);
            c1[cf] = fmaxf(c1[cf], nc);
          } else {
            if (posok) {
              float e = __expf(fmaf(-2.f, sim, 1.f));
              if (sim < tRx)      s0[rf * 4 + r] += e;
              if (sim < tBx[cf])  c0[cf] += e;
            } else if (!same) {
              float e = (sim > 0.22f) ? __expf(fmaf(50.f, sim, -25.f)) : 0.f;
              if (sim > tRn)      s1[rf * 4 + r] += 1e-30f + e;
              if (sim > tBn[cf])  c1[cf] += 1e-30f + e;
            }
          }
        }
      }
    }

    // col stats: reduce over quads (rows within wave), store per wave-half
    if (!diag) {
#pragma unroll
      for (int cf = 0; cf < 4; ++cf) {
        float v = c0[cf], w = c1[cf];
#pragma unroll
        for (int m = 16; m < 64; m <<= 1) {
          float vv = __shfl_xor(v, m), ww = __shfl_xor(w, m);
          v = (PASS == 1) ? fminf(v, vv) : (v + vv);
          w = (PASS == 1) ? fmaxf(w, ww) : (w + ww);
        }
        if (quad == 0) {
          size_t o = (size_t)t * 256 + (size_t)(wr >> 6) * 128 + wc + cf * 16 + l15;
          cp0[o] = v;
          cp1[o] = w;
        }
      }
    }
  }

  // ---- block end: row shuffle-reduce over l15, store per wave-half ----
#pragma unroll
  for (int i = 0; i < 16; ++i) {
#pragma unroll
    for (int m = 1; m < 16; m <<= 1) {
      float v = __shfl_xor(s0[i], m), w = __shfl_xor(s1[i], m);
      s0[i] = (PASS == 1) ? fminf(s0[i], v) : (s0[i] + v);
      s1[i] = (PASS == 1) ? fmaxf(s1[i], w) : (s1[i] + w);
    }
  }
  if (l15 == 0) {
#pragma unroll
    for (int rf = 0; rf < 4; ++rf)
#pragma unroll
      for (int r = 0; r < 4; ++r) {
        int ri = wr + rf * 16 + quad * 4 + r;
        size_t o = (size_t)blockIdx.x * 256 + (size_t)(wc >> 6) * 128 + ri;
        rp0[o] = s0[rf * 4 + r];
        rp1[o] = s1[rf * 4 + r];
      }
  }
}

// fold row-group partials (2 halves x ng groups) + col partials (2 x T tiles)
template <int PASS>
__global__ void reduce_kernel(const float* __restrict__ rp0, const float* __restrict__ rp1,
                              const float* __restrict__ cp0, const float* __restrict__ cp1,
                              float* __restrict__ o0, float* __restrict__ o1) {
  __shared__ float sA[128], sB[128];
  const int T = blockIdx.x;            // 64 strips
  const int q = threadIdx.x & 127;
  const int h = threadIdx.x >> 7;      // wave-half index
  int base = 0;
  for (int i = 0; i < T; ++i) base += (NT - i + GJT - 1) / GJT;
  const int ng = (NT - T + GJT - 1) / GJT;

  float a = (PASS == 1) ? __builtin_inff() : 0.f;
  float b = (PASS == 1) ? -__builtin_inff() : 0.f;
  for (int gg = 0; gg < ng; ++gg) {
    size_t o = (size_t)(base + gg) * 256 + (size_t)h * 128 + q;
    float v0 = rp0[o], v1 = rp1[o];
    a = (PASS == 1) ? fminf(a, v0) : (a + v0);
    b = (PASS == 1) ? fmaxf(b, v1) : (b + v1);
  }
  for (int Ip = 0; Ip < T; ++Ip) {
    size_t o = (size_t)(triBase(Ip) + (T - Ip)) * 256 + (size_t)h * 128 + q;
    float v0 = cp0[o], v1 = cp1[o];
    a = (PASS == 1) ? fminf(a, v0) : (a + v0);
    b = (PASS == 1) ? fmaxf(b, v1) : (b + v1);
  }
  if (h == 1) { sA[q] = a; sB[q] = b; }
  __syncthreads();
  if (h == 0) {
    a = (PASS == 1) ? fminf(a, sA[q]) : (a + sA[q]);
    b = (PASS == 1) ? fmaxf(b, sB[q]) : (b + sB[q]);
    if (PASS == 1) { o0[T * 128 + q] = a - 0.1f; o1[T * 128 + q] = b + 0.1f; }
    else           { o0[T * 128 + q] = a;        o1[T * 128 + q] = b; }
  }
}

__global__ void finalize_kernel(const float* __restrict__ psum, const float* __restrict__ nsum,
                                float* __restrict__ out, int Bn) {
  __shared__ float sl[4], sc2[4];
  float loss = 0.f, cnt = 0.f;
  for (int i = threadIdx.x; i < Bn; i += 256) {
    float p = psum[i], n = nsum[i];
    if (p > 0.f && n > 0.f) {
      loss += 0.5f * log1pf(p) + 0.02f * log1pf(n);
      cnt += 1.f;
    }
  }
#pragma unroll
  for (int m = 1; m < 64; m <<= 1) {
    loss += __shfl_xor(loss, m);
    cnt  += __shfl_xor(cnt, m);
  }
  int wave = threadIdx.x >> 6, lane = threadIdx.x & 63;
  if (lane == 0) { sl[wave] = loss; sc2[wave] = cnt; }
  __syncthreads();
  if (threadIdx.x == 0) {
    float L = sl[0] + sl[1] + sl[2] + sl[3];
    float C = sc2[0] + sc2[1] + sc2[2] + sc2[3];
    out[0] = L / (float)Bn;
    out[1] = 1.0f - C / (float)Bn;
  }
}

extern "C" void kernel_launch(void* const* d_in, const int* in_sizes, int n_in,
                              void* d_out, int out_size, void* d_ws, size_t ws_size,
                              hipStream_t stream) {
  const float* feats  = (const float*)d_in[0];
  const int*   labels = (const int*)d_in[1];
  const int Bn = in_sizes[1];          // 8192
  float* out = (float*)d_out;

  unsigned short* fb = (unsigned short*)d_ws;                       // 4 MB
  float* rp0  = (float*)((char*)d_ws + (size_t)Bn * D * 2);
  float* rp1  = rp0 + (size_t)NGRP * 256;
  float* cp0  = rp1 + (size_t)NGRP * 256;
  float* cp1  = cp0 + (size_t)NTILE * 256;
  float* tmn  = cp1 + (size_t)NTILE * 256;
  float* tmx  = tmn + Bn;
  float* psum = tmx + Bn;
  float* nsum = psum + Bn;

  int n4 = Bn * D / 4;
  convert_kernel<<<(n4 + 255) / 256, 256, 0, stream>>>(feats, fb, n4);

  pair_kernel<1><<<NGRP, 256, 0, stream>>>(fb, labels, nullptr, nullptr, rp0, rp1, cp0, cp1);
  reduce_kernel<1><<<NT, 256, 0, stream>>>(rp0, rp1, cp0, cp1, tmn, tmx);
  pair_kernel<2><<<NGRP, 256, 0, stream>>>(fb, labels, tmn, tmx, rp0, rp1, cp0, cp1);
  reduce_kernel<2><<<NT, 256, 0, stream>>>(rp0, rp1, cp0, cp1, psum, nsum);
  finalize_kernel<<<1, 256, 0, stream>>>(psum, nsum, out, Bn);
}

// Round 8
// 199.556 us; speedup vs baseline: 1.3741x; 1.3741x over previous
//
#include <hip/hip_runtime.h>
#include <stdint.h>

// ---------------------------------------------------------------------------
// Speaker pairwise loss. Half of sim = F·F^T via circulant band: strip I covers
// J=(I+off)%64, off in [0, 32] for I<32 and [0, 31] for I>=32 -> every unordered
// pair exactly once, 2080 tiles, near-equal strips (33/32).
// Grid = 64 strips x 8 groups = 512 EQUAL blocks (4-5 tiles, fixed I):
// R2's measured-best shape (5.4 us*CU/tile; row stats live in registers across
// the block, one flush). Col partials per tile, per wave-half (no barriers,
// no LDS scratch). Reduce kernels fold row+col partials; reduce2 also emits
// loss/prec1 via 2 atomics/block onto pre-initialized out (finalize merged).
// Staging: global_load_lds w=16, BK=64, XOR swizzle (0 conflicts, measured).
// NO forced min-waves bound (R5 spill disaster). Lessons: barrier count and
// dbuf neutral (R4/R6); block imbalance kills (R7: 11% occupancy).
// ws: fb bf16[B*D] | rp0/rp1[512*256] | cp0/cp1[2112*256] | tmn[B] tmx[B]
// ---------------------------------------------------------------------------

typedef __attribute__((ext_vector_type(8))) short short8;   // 8 bf16
typedef __attribute__((ext_vector_type(4))) float floatx4;  // MFMA C/D

constexpr int D = 256;
constexpr int BM = 128;
constexpr int NT = 64;                    // 8192/128 strips
constexpr int NPB = 512;                  // pair-kernel blocks (64 strips x 8)
constexpr int CPS = 33;                   // cp slots per strip (off 0..32)

__device__ __forceinline__ unsigned f2bf(float f) {  // fp32 -> bf16, RNE
  unsigned u = __float_as_uint(f);
  return (u + 0x7FFFu + ((u >> 16) & 1u)) >> 16;
}

__device__ __forceinline__ void gl_lds16(const void* g, void* l) {
  __builtin_amdgcn_global_load_lds(
      (const __attribute__((address_space(1))) unsigned int*)g,
      (__attribute__((address_space(3))) unsigned int*)l, 16, 0, 0);
}

__global__ void convert_kernel(const float* __restrict__ feats,
                               unsigned short* __restrict__ fb, int n4,
                               float* __restrict__ out) {
  int i = blockIdx.x * blockDim.x + threadIdx.x;
  if (i < n4) {
    float4 v = ((const float4*)feats)[i];
    unsigned lo = f2bf(v.x) | (f2bf(v.y) << 16);
    unsigned hi = f2bf(v.z) | (f2bf(v.w) << 16);
    ((uint2*)fb)[i] = make_uint2(lo, hi);
  }
  if (blockIdx.x == 0 && threadIdx.x == 0) { out[0] = 0.f; out[1] = 1.f; }
}

template <int PASS>
__global__ __launch_bounds__(256)
void pair_kernel(const unsigned short* __restrict__ fb, const int* __restrict__ labels,
                 const float* __restrict__ tmn, const float* __restrict__ tmx,
                 float* __restrict__ rp0, float* __restrict__ rp1,
                 float* __restrict__ cp0, float* __restrict__ cp1) {
  __shared__ __align__(16) short As[BM * 64];   // 16KB
  __shared__ __align__(16) short Bs[BM * 64];   // 16KB
  __shared__ int   labA[BM];
  __shared__ float tA0[BM], tA1[BM];

  const int bid = blockIdx.x;
  const int I   = bid >> 3;                 // strip (fixed per block)
  const int g   = bid & 7;
  const int nT  = (I < 32) ? 33 : 32;       // tiles in strip
  const int t0  = (g * nT) >> 3;
  const int t1  = ((g + 1) * nT) >> 3;      // 4 or 5 tiles
  const int row0 = I * BM;

  const int tid  = threadIdx.x;
  const int lane = tid & 63;
  const int wave = tid >> 6;
  const int l15  = lane & 15;
  const int quad = lane >> 4;
  const int wr   = (wave >> 1) * 64;
  const int wc   = (wave & 1) * 64;

  const float ONE_EPS = 1.0f - 1e-5f;
  const float INF = __builtin_inff();

  const int srow = (wave << 5) + (lane >> 3);   // staging: 8 lanes/row, 16B/lane
  const int slot = lane & 7;

  auto stage = [&](int kc, int col0) {
#pragma unroll
    for (int j = 0; j < 4; ++j) {
      int r = srow + 8 * j;
      int sw = (slot ^ (r & 7)) << 4;           // XOR swizzle (0 conflicts)
      const char* ga = (const char*)fb + (((size_t)(row0 + r)) << 9) + (kc << 7) + sw;
      const char* gb = (const char*)fb + (((size_t)(col0 + r)) << 9) + (kc << 7) + sw;
      gl_lds16(ga, (char*)As + (r << 7) + (slot << 4));
      gl_lds16(gb, (char*)Bs + (r << 7) + (slot << 4));
    }
  };

  if (tid < BM) {                               // once per block (covered by 1st sync)
    labA[tid] = labels[row0 + tid];
    if (PASS == 2) { tA0[tid] = tmn[row0 + tid]; tA1[tid] = tmx[row0 + tid]; }
  }

  int arow[4], brow[4];
#pragma unroll
  for (int i = 0; i < 4; ++i) {
    arow[i] = wr + i * 16 + l15;
    brow[i] = wc + i * 16 + l15;
  }

  // row stats: live in registers across the whole block (R2 pattern)
  float s0[16], s1[16];
#pragma unroll
  for (int i = 0; i < 16; ++i) {
    s0[i] = (PASS == 1) ? INF : 0.f;
    s1[i] = (PASS == 1) ? -INF : 0.f;
  }

  for (int off = t0; off < t1; ++off) {
    const int J = (I + off) & 63;
    const int col0 = J * BM;
    const bool diag = (off == 0);

    floatx4 acc[4][4];
#pragma unroll
    for (int rf = 0; rf < 4; ++rf)
#pragma unroll
      for (int cf = 0; cf < 4; ++cf)
        acc[rf][cf] = (floatx4)(0.f);

    for (int kc = 0; kc < 4; ++kc) {
      stage(kc, col0);
      __syncthreads();
#pragma unroll
      for (int ks = 0; ks < 2; ++ks) {
        const int gg = ks * 4 + quad;
        short8 a[4], b[4];
#pragma unroll
        for (int rf = 0; rf < 4; ++rf)
          a[rf] = *(const short8*)(As + arow[rf] * 64 + ((gg ^ (arow[rf] & 7)) << 3));
#pragma unroll
        for (int cf = 0; cf < 4; ++cf)
          b[cf] = *(const short8*)(Bs + brow[cf] * 64 + ((gg ^ (brow[cf] & 7)) << 3));
#pragma unroll
        for (int rf = 0; rf < 4; ++rf)
#pragma unroll
          for (int cf = 0; cf < 4; ++cf)
            acc[rf][cf] = __builtin_amdgcn_mfma_f32_16x16x32_bf16(a[rf], b[cf], acc[rf][cf], 0, 0, 0);
      }
      __syncthreads();
    }

    // col labels/thresholds loaded after K-loop (reduces live range)
    int labc[4];
    float tBn[4], tBx[4];
#pragma unroll
    for (int cf = 0; cf < 4; ++cf) {
      int ci = col0 + wc + cf * 16 + l15;
      labc[cf] = labels[ci];
      if (PASS == 2) { tBn[cf] = tmn[ci]; tBx[cf] = tmx[ci]; }
    }

    float c0[4], c1[4];
#pragma unroll
    for (int i = 0; i < 4; ++i) {
      c0[i] = (PASS == 1) ? INF : 0.f;
      c1[i] = (PASS == 1) ? -INF : 0.f;
    }

#pragma unroll
    for (int rf = 0; rf < 4; ++rf) {
#pragma unroll
      for (int r = 0; r < 4; ++r) {
        const int ri = wr + rf * 16 + quad * 4 + r;
        const int lr = labA[ri];
        float tRn = 0.f, tRx = 0.f;
        if (PASS == 2) { tRn = tA0[ri]; tRx = tA1[ri]; }
#pragma unroll
        for (int cf = 0; cf < 4; ++cf) {
          float sim = acc[rf][cf][r];
          bool same = (lr == labc[cf]);
          bool posok = same && (sim < ONE_EPS);
          if (PASS == 1) {
            float pc = posok ? sim : INF;
            float nc = same ? -INF : sim;
            s0[rf * 4 + r] = fminf(s0[rf * 4 + r], pc);
            s1[rf * 4 + r] = fmaxf(s1[rf * 4 + r], nc);
            c0[cf] = fminf(c0[cf], pc);
            c1[cf] = fmaxf(c1[cf], nc);
          } else {
            if (posok) {
              float e = __expf(fmaf(-2.f, sim, 1.f));
              if (sim < tRx)      s0[rf * 4 + r] += e;
              if (sim < tBx[cf])  c0[cf] += e;
            } else if (!same) {
              float e = (sim > 0.22f) ? __expf(fmaf(50.f, sim, -25.f)) : 0.f;
              if (sim > tRn)      s1[rf * 4 + r] += 1e-30f + e;
              if (sim > tBn[cf])  c1[cf] += 1e-30f + e;
            }
          }
        }
      }
    }

    // col flush per tile: reduce over quads, store per wave-half
    if (!diag) {
#pragma unroll
      for (int cf = 0; cf < 4; ++cf) {
        float v = c0[cf], w = c1[cf];
#pragma unroll
        for (int m = 16; m < 64; m <<= 1) {
          float vv = __shfl_xor(v, m), ww = __shfl_xor(w, m);
          v = (PASS == 1) ? fminf(v, vv) : (v + vv);
          w = (PASS == 1) ? fmaxf(w, ww) : (w + ww);
        }
        if (quad == 0) {
          size_t o = (size_t)(I * CPS + off) * 256 + (size_t)(wr >> 6) * 128 + wc + cf * 16 + l15;
          cp0[o] = v;
          cp1[o] = w;
        }
      }
    }
  }

  // row flush once per block: reduce over l15, store per wave-half
#pragma unroll
  for (int i = 0; i < 16; ++i) {
#pragma unroll
    for (int m = 1; m < 16; m <<= 1) {
      float v = __shfl_xor(s0[i], m), w = __shfl_xor(s1[i], m);
      s0[i] = (PASS == 1) ? fminf(s0[i], v) : (s0[i] + v);
      s1[i] = (PASS == 1) ? fmaxf(s1[i], w) : (s1[i] + w);
    }
  }
  if (l15 == 0) {
#pragma unroll
    for (int rf = 0; rf < 4; ++rf)
#pragma unroll
      for (int r = 0; r < 4; ++r) {
        int ri = wr + rf * 16 + quad * 4 + r;
        size_t o = (size_t)bid * 256 + (size_t)(wc >> 6) * 128 + ri;
        rp0[o] = s0[rf * 4 + r];
        rp1[o] = s1[rf * 4 + r];
      }
  }
}

// fold partials for strip T: 8 row blocks (bid=T*8+g) + col slots (I,off) with
// (I+off)%64==T, 1<=off<=lim(I). PASS1 -> thresholds; PASS2 -> loss atomics.
template <int PASS>
__global__ void reduce_kernel(const float* __restrict__ rp0, const float* __restrict__ rp1,
                              const float* __restrict__ cp0, const float* __restrict__ cp1,
                              float* __restrict__ o0, float* __restrict__ o1,
                              float* __restrict__ out) {
  __shared__ float sA[128], sB[128], sred[8];
  const int T = blockIdx.x;            // 64 strips
  const int q = threadIdx.x & 127;
  const int h = threadIdx.x >> 7;      // wave-half selector

  float a = (PASS == 1) ? __builtin_inff() : 0.f;
  float b = (PASS == 1) ? -__builtin_inff() : 0.f;
#pragma unroll
  for (int g = 0; g < 8; ++g) {
    size_t o = (size_t)(T * 8 + g) * 256 + (size_t)h * 128 + q;
    float v0 = rp0[o], v1 = rp1[o];
    a = (PASS == 1) ? fminf(a, v0) : (a + v0);
    b = (PASS == 1) ? fmaxf(b, v1) : (b + v1);
  }
  for (int I = 0; I < NT; ++I) {
    int off = (T - I) & 63;
    int lim = (I < 32) ? 32 : 31;
    if (off >= 1 && off <= lim) {
      size_t o = (size_t)(I * CPS + off) * 256 + (size_t)h * 128 + q;
      float v0 = cp0[o], v1 = cp1[o];
      a = (PASS == 1) ? fminf(a, v0) : (a + v0);
      b = (PASS == 1) ? fmaxf(b, v1) : (b + v1);
    }
  }
  if (h == 1) { sA[q] = a; sB[q] = b; }
  __syncthreads();
  if (h == 0) {
    a = (PASS == 1) ? fminf(a, sA[q]) : (a + sA[q]);
    b = (PASS == 1) ? fmaxf(b, sB[q]) : (b + sB[q]);
    if (PASS == 1) {
      o0[T * 128 + q] = a - 0.1f;   // min_pos - MARGIN (inf-safe)
      o1[T * 128 + q] = b + 0.1f;   // max_neg + MARGIN
    } else {
      // finalize fused: per-row loss, block-reduce, 2 atomics
      float loss = 0.f, cnt = 0.f;
      if (a > 0.f && b > 0.f) {
        loss = 0.5f * log1pf(a) + 0.02f * log1pf(b);
        cnt = 1.f;
      }
#pragma unroll
      for (int m = 1; m < 64; m <<= 1) {
        loss += __shfl_xor(loss, m);
        cnt  += __shfl_xor(cnt, m);
      }
      int wv = threadIdx.x >> 6, ln = threadIdx.x & 63;
      if (ln == 0) { sred[wv] = loss; sred[4 + wv] = cnt; }
    }
  }
  if (PASS == 2) {
    __syncthreads();
    if (threadIdx.x == 0) {
      float L = sred[0] + sred[1];
      float C = sred[4] + sred[5];
      atomicAdd(out, L / 8192.0f);
      atomicAdd(out + 1, -C / 8192.0f);
    }
  }
}

extern "C" void kernel_launch(void* const* d_in, const int* in_sizes, int n_in,
                              void* d_out, int out_size, void* d_ws, size_t ws_size,
                              hipStream_t stream) {
  const float* feats  = (const float*)d_in[0];
  const int*   labels = (const int*)d_in[1];
  const int Bn = in_sizes[1];          // 8192
  float* out = (float*)d_out;

  unsigned short* fb = (unsigned short*)d_ws;                       // 4 MB
  float* rp0 = (float*)((char*)d_ws + (size_t)Bn * D * 2);
  float* rp1 = rp0 + (size_t)NPB * 256;
  float* cp0 = rp1 + (size_t)NPB * 256;
  float* cp1 = cp0 + (size_t)NT * CPS * 256;
  float* tmn = cp1 + (size_t)NT * CPS * 256;
  float* tmx = tmn + Bn;

  int n4 = Bn * D / 4;
  convert_kernel<<<(n4 + 255) / 256, 256, 0, stream>>>(feats, fb, n4, out);

  pair_kernel<1><<<NPB, 256, 0, stream>>>(fb, labels, nullptr, nullptr, rp0, rp1, cp0, cp1);
  reduce_kernel<1><<<NT, 256, 0, stream>>>(rp0, rp1, cp0, cp1, tmn, tmx, out);
  pair_kernel<2><<<NPB, 256, 0, stream>>>(fb, labels, tmn, tmx, rp0, rp1, cp0, cp1);
  reduce_kernel<2><<<NT, 256, 0, stream>>>(rp0, rp1, cp0, cp1, nullptr, nullptr, out);
}

// Round 9
// 198.105 us; speedup vs baseline: 1.3842x; 1.0073x over previous
//
#include <hip/hip_runtime.h>
#include <hip/hip_cooperative_groups.h>
#include <stdint.h>

namespace cg = cooperative_groups;

// ---------------------------------------------------------------------------
// Speaker pairwise loss. R9 = R8's proven structure (circulant-band half
// matrix, 512 equal blocks, register-resident row stats, per-wave-half
// partial stores, no atomics in hot path) fused into ONE cooperative kernel:
// phases convert | pass1 | reduce1 | pass2 | reduce2+finalize, grid.sync
// between. R8 measured 123.6us of pair work inside 199.6us total -> ~76us of
// launch gaps/small kernels; fusion converts that to ~4 grid syncs.
// R5 lesson: fusion failed ONLY because __launch_bounds__(256,4) capped VGPR
// at 64 and spilled the 64-reg accumulator. No min-waves bound here. VGPR
// ~148 -> 3 blocks/CU, LDS 33KB -> 4/CU; 512-block coop launch fits even at
// VGPR 256 (2 blocks/CU x 256 CU). Runtime fallback to split path if not.
// ws: fb bf16[B*D] | rp0/rp1[512*256] | cp0/cp1[64*33*256] | tmn[B] tmx[B]
// ---------------------------------------------------------------------------

typedef __attribute__((ext_vector_type(8))) short short8;   // 8 bf16
typedef __attribute__((ext_vector_type(4))) float floatx4;  // MFMA C/D

constexpr int D = 256;
constexpr int BM = 128;
constexpr int NT = 64;                    // 8192/128 strips
constexpr int NPB = 512;                  // pair blocks (64 strips x 8)
constexpr int CPS = 33;                   // cp slots per strip (off 0..32)

__device__ __forceinline__ unsigned f2bf(float f) {  // fp32 -> bf16, RNE
  unsigned u = __float_as_uint(f);
  return (u + 0x7FFFu + ((u >> 16) & 1u)) >> 16;
}

__device__ __forceinline__ void gl_lds16(const void* g, void* l) {
  __builtin_amdgcn_global_load_lds(
      (const __attribute__((address_space(1))) unsigned int*)g,
      (__attribute__((address_space(3))) unsigned int*)l, 16, 0, 0);
}

// ---------------- pair body (identical logic to R8, measured 61.8us) --------
template <int PASS>
__device__ __forceinline__ void pair_body(
    int bid, const unsigned short* __restrict__ fb, const int* __restrict__ labels,
    const float* __restrict__ tmn, const float* __restrict__ tmx,
    float* __restrict__ rp0, float* __restrict__ rp1,
    float* __restrict__ cp0, float* __restrict__ cp1,
    short* As, short* Bs, int* labA, float* tA0, float* tA1) {
  const int I   = bid >> 3;
  const int g   = bid & 7;
  const int nT  = (I < 32) ? 33 : 32;
  const int t0  = (g * nT) >> 3;
  const int t1  = ((g + 1) * nT) >> 3;
  const int row0 = I * BM;

  const int tid  = threadIdx.x;
  const int lane = tid & 63;
  const int wave = tid >> 6;
  const int l15  = lane & 15;
  const int quad = lane >> 4;
  const int wr   = (wave >> 1) * 64;
  const int wc   = (wave & 1) * 64;

  const float ONE_EPS = 1.0f - 1e-5f;
  const float INF = __builtin_inff();

  const int srow = (wave << 5) + (lane >> 3);
  const int slot = lane & 7;

  __syncthreads();                       // protect smem vs previous phase
  if (tid < BM) {
    labA[tid] = labels[row0 + tid];
    if (PASS == 2) { tA0[tid] = tmn[row0 + tid]; tA1[tid] = tmx[row0 + tid]; }
  }

  int arow[4], brow[4];
#pragma unroll
  for (int i = 0; i < 4; ++i) {
    arow[i] = wr + i * 16 + l15;
    brow[i] = wc + i * 16 + l15;
  }

  float s0[16], s1[16];
#pragma unroll
  for (int i = 0; i < 16; ++i) {
    s0[i] = (PASS == 1) ? INF : 0.f;
    s1[i] = (PASS == 1) ? -INF : 0.f;
  }

  for (int off = t0; off < t1; ++off) {
    const int J = (I + off) & 63;
    const int col0 = J * BM;
    const bool diag = (off == 0);

    floatx4 acc[4][4];
#pragma unroll
    for (int rf = 0; rf < 4; ++rf)
#pragma unroll
      for (int cf = 0; cf < 4; ++cf)
        acc[rf][cf] = (floatx4)(0.f);

    for (int kc = 0; kc < 4; ++kc) {
#pragma unroll
      for (int j = 0; j < 4; ++j) {
        int r = srow + 8 * j;
        int sw = (slot ^ (r & 7)) << 4;  // XOR swizzle (0 conflicts, measured)
        const char* ga = (const char*)fb + (((size_t)(row0 + r)) << 9) + (kc << 7) + sw;
        const char* gb = (const char*)fb + (((size_t)(col0 + r)) << 9) + (kc << 7) + sw;
        gl_lds16(ga, (char*)As + (r << 7) + (slot << 4));
        gl_lds16(gb, (char*)Bs + (r << 7) + (slot << 4));
      }
      __syncthreads();
#pragma unroll
      for (int ks = 0; ks < 2; ++ks) {
        const int gg = ks * 4 + quad;
        short8 a[4], b[4];
#pragma unroll
        for (int rf = 0; rf < 4; ++rf)
          a[rf] = *(const short8*)(As + arow[rf] * 64 + ((gg ^ (arow[rf] & 7)) << 3));
#pragma unroll
        for (int cf = 0; cf < 4; ++cf)
          b[cf] = *(const short8*)(Bs + brow[cf] * 64 + ((gg ^ (brow[cf] & 7)) << 3));
#pragma unroll
        for (int rf = 0; rf < 4; ++rf)
#pragma unroll
          for (int cf = 0; cf < 4; ++cf)
            acc[rf][cf] = __builtin_amdgcn_mfma_f32_16x16x32_bf16(a[rf], b[cf], acc[rf][cf], 0, 0, 0);
      }
      __syncthreads();
    }

    int labc[4];
    float tBn[4], tBx[4];
#pragma unroll
    for (int cf = 0; cf < 4; ++cf) {
      int ci = col0 + wc + cf * 16 + l15;
      labc[cf] = labels[ci];
      if (PASS == 2) { tBn[cf] = tmn[ci]; tBx[cf] = tmx[ci]; }
    }

    float c0[4], c1[4];
#pragma unroll
    for (int i = 0; i < 4; ++i) {
      c0[i] = (PASS == 1) ? INF : 0.f;
      c1[i] = (PASS == 1) ? -INF : 0.f;
    }

#pragma unroll
    for (int rf = 0; rf < 4; ++rf) {
#pragma unroll
      for (int r = 0; r < 4; ++r) {
        const int ri = wr + rf * 16 + quad * 4 + r;
        const int lr = labA[ri];
        float tRn = 0.f, tRx = 0.f;
        if (PASS == 2) { tRn = tA0[ri]; tRx = tA1[ri]; }
#pragma unroll
        for (int cf = 0; cf < 4; ++cf) {
          float sim = acc[rf][cf][r];
          bool same = (lr == labc[cf]);
          bool posok = same && (sim < ONE_EPS);
          if (PASS == 1) {
            float pc = posok ? sim : INF;
            float nc = same ? -INF : sim;
            s0[rf * 4 + r] = fminf(s0[rf * 4 + r], pc);
            s1[rf * 4 + r] = fmaxf(s1[rf * 4 + r], nc);
            c0[cf] = fminf(c0[cf], pc);
            c1[cf] = fmaxf(c1[cf], nc);
          } else {
            if (posok) {
              float e = __expf(fmaf(-2.f, sim, 1.f));
              if (sim < tRx)      s0[rf * 4 + r] += e;
              if (sim < tBx[cf])  c0[cf] += e;
            } else if (!same) {
              float e = (sim > 0.22f) ? __expf(fmaf(50.f, sim, -25.f)) : 0.f;
              if (sim > tRn)      s1[rf * 4 + r] += 1e-30f + e;
              if (sim > tBn[cf])  c1[cf] += 1e-30f + e;
            }
          }
        }
      }
    }

    if (!diag) {
#pragma unroll
      for (int cf = 0; cf < 4; ++cf) {
        float v = c0[cf], w = c1[cf];
#pragma unroll
        for (int m = 16; m < 64; m <<= 1) {
          float vv = __shfl_xor(v, m), ww = __shfl_xor(w, m);
          v = (PASS == 1) ? fminf(v, vv) : (v + vv);
          w = (PASS == 1) ? fmaxf(w, ww) : (w + ww);
        }
        if (quad == 0) {
          size_t o = (size_t)(I * CPS + off) * 256 + (size_t)(wr >> 6) * 128 + wc + cf * 16 + l15;
          cp0[o] = v;
          cp1[o] = w;
        }
      }
    }
  }

#pragma unroll
  for (int i = 0; i < 16; ++i) {
#pragma unroll
    for (int m = 1; m < 16; m <<= 1) {
      float v = __shfl_xor(s0[i], m), w = __shfl_xor(s1[i], m);
      s0[i] = (PASS == 1) ? fminf(s0[i], v) : (s0[i] + v);
      s1[i] = (PASS == 1) ? fmaxf(s1[i], w) : (s1[i] + w);
    }
  }
  if (l15 == 0) {
#pragma unroll
    for (int rf = 0; rf < 4; ++rf)
#pragma unroll
      for (int r = 0; r < 4; ++r) {
        int ri = wr + rf * 16 + quad * 4 + r;
        size_t o = (size_t)bid * 256 + (size_t)(wc >> 6) * 128 + ri;
        rp0[o] = s0[rf * 4 + r];
        rp1[o] = s1[rf * 4 + r];
      }
  }
}

// ---------------- reduce body (R8 logic) -----------------------------------
template <int PASS>
__device__ __forceinline__ void reduce_body(
    int T, const float* __restrict__ rp0, const float* __restrict__ rp1,
    const float* __restrict__ cp0, const float* __restrict__ cp1,
    float* __restrict__ o0, float* __restrict__ o1, float* __restrict__ out,
    float* sA, float* sB, float* sred) {
  const int q = threadIdx.x & 127;
  const int h = threadIdx.x >> 7;

  float a = (PASS == 1) ? __builtin_inff() : 0.f;
  float b = (PASS == 1) ? -__builtin_inff() : 0.f;
#pragma unroll
  for (int g = 0; g < 8; ++g) {
    size_t o = (size_t)(T * 8 + g) * 256 + (size_t)h * 128 + q;
    float v0 = rp0[o], v1 = rp1[o];
    a = (PASS == 1) ? fminf(a, v0) : (a + v0);
    b = (PASS == 1) ? fmaxf(b, v1) : (b + v1);
  }
  for (int I = 0; I < NT; ++I) {
    int off = (T - I) & 63;
    int lim = (I < 32) ? 32 : 31;
    if (off >= 1 && off <= lim) {
      size_t o = (size_t)(I * CPS + off) * 256 + (size_t)h * 128 + q;
      float v0 = cp0[o], v1 = cp1[o];
      a = (PASS == 1) ? fminf(a, v0) : (a + v0);
      b = (PASS == 1) ? fmaxf(b, v1) : (b + v1);
    }
  }
  if (h == 1) { sA[q] = a; sB[q] = b; }
  __syncthreads();
  if (h == 0) {
    a = (PASS == 1) ? fminf(a, sA[q]) : (a + sA[q]);
    b = (PASS == 1) ? fmaxf(b, sB[q]) : (b + sB[q]);
    if (PASS == 1) {
      o0[T * 128 + q] = a - 0.1f;
      o1[T * 128 + q] = b + 0.1f;
    } else {
      float loss = 0.f, cnt = 0.f;
      if (a > 0.f && b > 0.f) {
        loss = 0.5f * log1pf(a) + 0.02f * log1pf(b);
        cnt = 1.f;
      }
#pragma unroll
      for (int m = 1; m < 64; m <<= 1) {
        loss += __shfl_xor(loss, m);
        cnt  += __shfl_xor(cnt, m);
      }
      int wv = threadIdx.x >> 6, ln = threadIdx.x & 63;
      if (ln == 0) { sred[wv] = loss; sred[4 + wv] = cnt; }
    }
  }
  if (PASS == 2) {
    __syncthreads();
    if (threadIdx.x == 0) {
      float L = sred[0] + sred[1];
      float C = sred[4] + sred[5];
      atomicAdd(out, L / 8192.0f);
      atomicAdd(out + 1, -C / 8192.0f);
    }
  }
}

// ---------------- fused cooperative kernel ---------------------------------
__global__ __launch_bounds__(256)
void mega_kernel(const float* feats, const int* labels, unsigned short* fb,
                 float* rp0, float* rp1, float* cp0, float* cp1,
                 float* tmn, float* tmx, float* out) {
  __shared__ __align__(16) short As[BM * 64];
  __shared__ __align__(16) short Bs[BM * 64];
  __shared__ int   labA[BM];
  __shared__ float tA0[BM], tA1[BM];

  cg::grid_group grid = cg::this_grid();
  const int bid = blockIdx.x;
  const int tid = threadIdx.x;

  // phase 0: convert fp32 -> bf16 (+ init out)
  const int n4 = 8192 * D / 4;
  for (int i = bid * 256 + tid; i < n4; i += NPB * 256) {
    float4 v = ((const float4*)feats)[i];
    unsigned lo = f2bf(v.x) | (f2bf(v.y) << 16);
    unsigned hi = f2bf(v.z) | (f2bf(v.w) << 16);
    ((uint2*)fb)[i] = make_uint2(lo, hi);
  }
  if (bid == 0 && tid == 0) { out[0] = 0.f; out[1] = 1.f; }
  __threadfence();
  grid.sync();

  // phase 1: pass1
  pair_body<1>(bid, fb, labels, nullptr, nullptr, rp0, rp1, cp0, cp1,
               As, Bs, labA, tA0, tA1);
  __threadfence();
  grid.sync();

  // phase 2: reduce1 -> thresholds
  if (bid < NT)
    reduce_body<1>(bid, rp0, rp1, cp0, cp1, tmn, tmx, out,
                   (float*)As, (float*)As + 128, (float*)As + 256);
  __threadfence();
  grid.sync();

  // phase 3: pass2
  pair_body<2>(bid, fb, labels, tmn, tmx, rp0, rp1, cp0, cp1,
               As, Bs, labA, tA0, tA1);
  __threadfence();
  grid.sync();

  // phase 4: reduce2 + finalize (atomics onto out)
  if (bid < NT)
    reduce_body<2>(bid, rp0, rp1, cp0, cp1, nullptr, nullptr, out,
                   (float*)As, (float*)As + 128, (float*)As + 256);
}

// ---------------- fallback split kernels (R8, proven 199.6us) --------------
__global__ void convert_kernel(const float* __restrict__ feats,
                               unsigned short* __restrict__ fb, int n4,
                               float* __restrict__ out) {
  int i = blockIdx.x * blockDim.x + threadIdx.x;
  if (i < n4) {
    float4 v = ((const float4*)feats)[i];
    unsigned lo = f2bf(v.x) | (f2bf(v.y) << 16);
    unsigned hi = f2bf(v.z) | (f2bf(v.w) << 16);
    ((uint2*)fb)[i] = make_uint2(lo, hi);
  }
  if (blockIdx.x == 0 && threadIdx.x == 0) { out[0] = 0.f; out[1] = 1.f; }
}

template <int PASS>
__global__ __launch_bounds__(256)
void pair_kernel(const unsigned short* __restrict__ fb, const int* __restrict__ labels,
                 const float* __restrict__ tmn, const float* __restrict__ tmx,
                 float* __restrict__ rp0, float* __restrict__ rp1,
                 float* __restrict__ cp0, float* __restrict__ cp1) {
  __shared__ __align__(16) short As[BM * 64];
  __shared__ __align__(16) short Bs[BM * 64];
  __shared__ int   labA[BM];
  __shared__ float tA0[BM], tA1[BM];
  pair_body<PASS>(blockIdx.x, fb, labels, tmn, tmx, rp0, rp1, cp0, cp1,
                  As, Bs, labA, tA0, tA1);
}

template <int PASS>
__global__ void reduce_kernel(const float* __restrict__ rp0, const float* __restrict__ rp1,
                              const float* __restrict__ cp0, const float* __restrict__ cp1,
                              float* __restrict__ o0, float* __restrict__ o1,
                              float* __restrict__ out) {
  __shared__ float sA[128], sB[128], sred[8];
  reduce_body<PASS>(blockIdx.x, rp0, rp1, cp0, cp1, o0, o1, out, sA, sB, sred);
}

extern "C" void kernel_launch(void* const* d_in, const int* in_sizes, int n_in,
                              void* d_out, int out_size, void* d_ws, size_t ws_size,
                              hipStream_t stream) {
  const float* feats  = (const float*)d_in[0];
  const int*   labels = (const int*)d_in[1];
  const int Bn = in_sizes[1];          // 8192
  float* out = (float*)d_out;

  unsigned short* fb = (unsigned short*)d_ws;                       // 4 MB
  float* rp0 = (float*)((char*)d_ws + (size_t)Bn * D * 2);
  float* rp1 = rp0 + (size_t)NPB * 256;
  float* cp0 = rp1 + (size_t)NPB * 256;
  float* cp1 = cp0 + (size_t)NT * CPS * 256;
  float* tmn = cp1 + (size_t)NT * CPS * 256;
  float* tmx = tmn + Bn;

  int maxb = 0;
  hipOccupancyMaxActiveBlocksPerMultiprocessor(&maxb, (const void*)mega_kernel, 256, 0);
  if (maxb * 256 >= NPB) {
    void* args[] = {(void*)&feats, (void*)&labels, (void*)&fb,
                    (void*)&rp0, (void*)&rp1, (void*)&cp0, (void*)&cp1,
                    (void*)&tmn, (void*)&tmx, (void*)&out};
    hipLaunchCooperativeKernel((const void*)mega_kernel, dim3(NPB), dim3(256), args, 0, stream);
  } else {
    int n4 = Bn * D / 4;
    convert_kernel<<<(n4 + 255) / 256, 256, 0, stream>>>(feats, fb, n4, out);
    pair_kernel<1><<<NPB, 256, 0, stream>>>(fb, labels, nullptr, nullptr, rp0, rp1, cp0, cp1);
    reduce_kernel<1><<<NT, 256, 0, stream>>>(rp0, rp1, cp0, cp1, tmn, tmx, out);
    pair_kernel<2><<<NPB, 256, 0, stream>>>(fb, labels, tmn, tmx, rp0, rp1, cp0, cp1);
    reduce_kernel<2><<<NT, 256, 0, stream>>>(rp0, rp1, cp0, cp1, nullptr, nullptr, out);
  }
}